// Round 9
// baseline (411.676 us; speedup 1.0000x reference)
//
#include <hip/hip_runtime.h>

#define NN 100000
#define EE 1600000
#define DTc 0.1f
#define REGc 1e-6f
#define WQc (1.0f / 64.0f)

#define NB 782              // ceil(NN/128) buckets of 128 nodes
#define CHUNK 8192          // edges per binning block
#define NCH 196             // ceil(EE/CHUNK)
#define SC_NB 300           // scan blocks of 512 over the matrix
#define MPAD (SC_NB * 512)  // 153600 >= NB*NCH = 153272 (pad zeroed)
#define TENT (2 * EE)       // combined incidence entries
#define ACT_S 72            // padded LDS row stride (bf16) in node_kernel
#define PRE_NB 6250         // NN*16/256 exact
#define WP_NB 80            // 5*4096/256 exact
#define CAP 6144            // bucket_sort LDS staging capacity (48 KB)

typedef unsigned long long u64;
typedef __attribute__((ext_vector_type(8))) short short8;
typedef __attribute__((ext_vector_type(4))) float f32x4;
typedef __attribute__((ext_vector_type(2))) float f32x2;

__device__ __forceinline__ unsigned short f2bf(float x) {
    unsigned u = __float_as_uint(x);
    unsigned r = (u + 0x7fffu + ((u >> 16) & 1u)) >> 16;   // RNE
    return (unsigned short)r;
}
__device__ __forceinline__ float bf2f(unsigned short s) {
    return __uint_as_float(((unsigned)s) << 16);
}

// ---------------------------------------------------------------------------
// Merged prep: blocks [0,PRE_NB): f+ = relu(f) as bf16 AND fp8-e4m3
// (4 elems/thread); blocks [PRE_NB, ...): transposed bf16 weights.
// ---------------------------------------------------------------------------
__global__ __launch_bounds__(256) void prep_kernel(
    const float* __restrict__ f, unsigned int* __restrict__ fb16u,
    unsigned int* __restrict__ f8u,
    const float* __restrict__ w_in, const float* __restrict__ w_hid,
    const float* __restrict__ w_out, unsigned short* __restrict__ wp) {
    int b = blockIdx.x;
    if (b < PRE_NB) {
        int i = b * 256 + threadIdx.x;          // < NN*16 exactly
        float4 v = *(const float4*)&f[i * 4];
        float x0 = fmaxf(v.x, 0.f), x1 = fmaxf(v.y, 0.f);
        float x2 = fmaxf(v.z, 0.f), x3 = fmaxf(v.w, 0.f);
        unsigned lo = (unsigned)f2bf(x0) | ((unsigned)f2bf(x1) << 16);
        unsigned hi = (unsigned)f2bf(x2) | ((unsigned)f2bf(x3) << 16);
        fb16u[i * 2] = lo;
        fb16u[i * 2 + 1] = hi;
        int p = 0;
        p = __builtin_amdgcn_cvt_pk_fp8_f32(x0, x1, p, false);
        p = __builtin_amdgcn_cvt_pk_fp8_f32(x2, x3, p, true);
        f8u[i] = (unsigned)p;
    } else {
        int i = (b - PRE_NB) * 256 + threadIdx.x;   // < 5*4096 exactly
        int l = i >> 12, idx = i & 4095;
        int n = idx >> 6, k = idx & 63;
        const float* W = (l == 0) ? w_in : (l < 4 ? w_hid + (l - 1) * 4096 : w_out);
        wp[i] = f2bf(W[k * 64 + n]);
    }
}

// ---------------------------------------------------------------------------
// Per-chunk bucket counts -> bc[bucket*NCH + chunk]; fused out-degree hist.
// ---------------------------------------------------------------------------
__global__ __launch_bounds__(256) void bin_count(const int* __restrict__ esrc,
                                                 const int* __restrict__ edst,
                                                 int* __restrict__ bc,
                                                 int* __restrict__ deg) {
    __shared__ int cnt[NB];
    int t = threadIdx.x;
    for (int j = t; j < NB; j += 256) cnt[j] = 0;
    __syncthreads();
    int base = blockIdx.x * CHUNK;
    int nE = min(CHUNK, EE - base);
    for (int i = t; i < nE; i += 256) {
        int s = esrc[base + i], d = edst[base + i];
        atomicAdd(&cnt[s >> 7], 1);
        atomicAdd(&cnt[d >> 7], 1);
        atomicAdd(&deg[s], 1);
    }
    __syncthreads();
    for (int j = t; j < NB; j += 256) bc[j * NCH + blockIdx.x] = cnt[j];
}

// ---------------------------------------------------------------------------
// 2-kernel scan over MPAD elements (block offsets applied inline downstream)
// ---------------------------------------------------------------------------
__global__ __launch_bounds__(512) void scan_blocks(const int* __restrict__ in,
                                                   int* __restrict__ out,
                                                   int* __restrict__ bsums) {
    __shared__ int s[512];
    int t = threadIdx.x;
    int i = blockIdx.x * 512 + t;
    int v = in[i];
    s[t] = v;
    __syncthreads();
    for (int o = 1; o < 512; o <<= 1) {
        int x = (t >= o) ? s[t - o] : 0;
        __syncthreads();
        s[t] += x;
        __syncthreads();
    }
    out[i] = s[t] - v;
    if (t == 0) bsums[blockIdx.x] = s[511];
}

__global__ __launch_bounds__(512) void scan_sums(int* __restrict__ bsums) {
    __shared__ int s[512];
    int t = threadIdx.x;
    int v = (t < SC_NB) ? bsums[t] : 0;
    s[t] = v;
    __syncthreads();
    for (int o = 1; o < 512; o <<= 1) {
        int x = (t >= o) ? s[t - o] : 0;
        __syncthreads();
        s[t] += x;
        __syncthreads();
    }
    if (t < SC_NB) bsums[t] = s[t] - v;
}

// ---------------------------------------------------------------------------
// Binned scatter: chunk re-reads its edges, appends entries into its PRIVATE
// [chunk][bucket] ranges via LDS cursors. entry = (f32 q)<<32 | local<<17 | other
// Block-offset add (old add_offsets) fused into the cursor init.
// ---------------------------------------------------------------------------
__global__ __launch_bounds__(256) void bin_scatter(
    const int* __restrict__ esrc, const int* __restrict__ edst,
    const float* __restrict__ ew, const int* __restrict__ deg,
    const int* __restrict__ offs, const int* __restrict__ bsums,
    u64* __restrict__ adj64) {
    __shared__ int cur[NB];
    int t = threadIdx.x, blk = blockIdx.x;
    for (int j = t; j < NB; j += 256) {
        int idx = j * NCH + blk;
        cur[j] = offs[idx] + bsums[idx >> 9];
    }
    __syncthreads();
    int base = blk * CHUNK;
    int nE = min(CHUNK, EE - base);
    for (int i = t; i < nE; i += 256) {
        int s = esrc[base + i], d = edst[base + i];
        float q = ew[base + i] / (float)deg[s];
        u64 qb = ((u64)__float_as_uint(q)) << 32;
        int p1 = atomicAdd(&cur[s >> 7], 1);
        adj64[p1] = qb | (unsigned)(d | ((s & 127) << 17));
        int p2 = atomicAdd(&cur[d >> 7], 1);
        adj64[p2] = qb | (unsigned)(s | ((d & 127) << 17));
    }
}

// ---------------------------------------------------------------------------
// Per-bucket sort -> per-node CSR of 4B packed (q15<<17 | other) entries.
// Entries staged once in LDS (<=CAP) so pass 2 re-reads LDS not global;
// global-path fallback keeps correctness for any degree distribution.
// ---------------------------------------------------------------------------
__global__ __launch_bounds__(256) void bucket_sort(
    const int* __restrict__ offs, const int* __restrict__ bsums,
    const u64* __restrict__ adj64,
    unsigned int* __restrict__ adj4, int* __restrict__ node_offs) {
    __shared__ u64 ebuf[CAP];
    __shared__ int cnt[128], sc[128], base[128];
    int t = threadIdx.x, b = blockIdx.x;
    if (t < 128) cnt[t] = 0;
    __syncthreads();
    int i0 = b * NCH, i1 = (b + 1) * NCH;      // i1 <= NB*NCH < MPAD (pad zeroed)
    int start = offs[i0] + bsums[i0 >> 9];
    int end   = offs[i1] + bsums[i1 >> 9];
    int len = end - start;
    if (len <= CAP) {
        for (int i = t; i < len; i += 256) {
            u64 e = adj64[start + i];
            ebuf[i] = e;
            atomicAdd(&cnt[((unsigned)e >> 17) & 127], 1);
        }
    } else {
        for (int i = start + t; i < end; i += 256)
            atomicAdd(&cnt[((unsigned)adj64[i] >> 17) & 127], 1);
    }
    __syncthreads();
    if (t < 128) sc[t] = cnt[t];
    __syncthreads();
    for (int o = 1; o < 128; o <<= 1) {
        int x = 0;
        if (t < 128 && t >= o) x = sc[t - o];
        __syncthreads();
        if (t < 128) sc[t] += x;
        __syncthreads();
    }
    if (t < 128) {
        base[t] = start + sc[t] - cnt[t];   // exclusive
        int n = b * 128 + t;
        if (n < NN) node_offs[n] = base[t];
        cnt[t] = 0;                          // reuse as cursor
    }
    if (b == 0 && t == 0) node_offs[NN] = TENT;
    __syncthreads();
    if (len <= CAP) {
        for (int i = t; i < len; i += 256) {
            u64 e = ebuf[i];
            unsigned lo = (unsigned)e;
            int local = (lo >> 17) & 127;
            float q = __uint_as_float((unsigned)(e >> 32));
            unsigned q15 = (unsigned)(q * 32768.f + 0.5f);
            if (q15 > 32767u) q15 = 32767u;
            int p = base[local] + atomicAdd(&cnt[local], 1);
            adj4[p] = (q15 << 17) | (lo & 0x1FFFFu);
        }
    } else {
        for (int i = start + t; i < end; i += 256) {
            u64 e = adj64[i];
            unsigned lo = (unsigned)e;
            int local = (lo >> 17) & 127;
            float q = __uint_as_float((unsigned)(e >> 32));
            unsigned q15 = (unsigned)(q * 32768.f + 0.5f);
            if (q15 > 32767u) q15 = 32767u;
            int p = base[local] + atomicAdd(&cnt[local], 1);
            adj4[p] = (q15 << 17) | (lo & 0x1FFFFu);
        }
    }
}

// ---------------------------------------------------------------------------
// Gather transport: one wave per node, QUARTER-WAVE per entry, fp8 rows.
// Row = 64 B: lane c in [0,16) loads one uint = 4 fp8 bins (4c..4c+3).
// HW cvt_pk_f32_fp8 unpacks 2 bins/op. Cross-quarter shfl reduce at end.
// f_o and f_n both read from the SAME fp8 quantization (exact cancellation
// when f_o == f_n).
// ---------------------------------------------------------------------------
__global__ __launch_bounds__(256) void gather_kernel(
    const unsigned int* __restrict__ f8u, const int* __restrict__ node_offs,
    const unsigned int* __restrict__ adj, const float* __restrict__ xi,
    float* __restrict__ trans) {
    const float QS = 1.f / 32768.f;
    int lane = threadIdx.x & 63;
    int n = blockIdx.x * 4 + (threadIdx.x >> 6);
    if (n >= NN) return;
    int c = lane & 15;     // uint column: bins 4c..4c+3
    int qt = lane >> 4;    // quarter index: entry j+qt
    int j = node_offs[n];
    int end = node_offs[n + 1];
    float a0 = 0.f, a1 = 0.f, a2 = 0.f, a3 = 0.f, qs = 0.f;
    for (; j + 4 <= end; j += 4) {
        unsigned e = adj[j + qt];
        unsigned r = f8u[(e & 0x1FFFFu) * 16 + c];
        float q = (float)(e >> 17) * QS;
        f32x2 lo = __builtin_amdgcn_cvt_pk_f32_fp8(r, false);
        f32x2 hi = __builtin_amdgcn_cvt_pk_f32_fp8(r, true);
        a0 = fmaf(q, lo.x, a0);
        a1 = fmaf(q, lo.y, a1);
        a2 = fmaf(q, hi.x, a2);
        a3 = fmaf(q, hi.y, a3);
        qs += q;
    }
    if (j < end) {                       // tail: 1..3 entries, quarter-guarded
        int idx = j + qt;
        bool ok = idx < end;
        unsigned e = ok ? adj[idx] : 0u;
        unsigned r = f8u[(e & 0x1FFFFu) * 16 + c];
        float q = ok ? (float)(e >> 17) * QS : 0.f;
        f32x2 lo = __builtin_amdgcn_cvt_pk_f32_fp8(r, false);
        f32x2 hi = __builtin_amdgcn_cvt_pk_f32_fp8(r, true);
        a0 = fmaf(q, lo.x, a0);
        a1 = fmaf(q, lo.y, a1);
        a2 = fmaf(q, hi.x, a2);
        a3 = fmaf(q, hi.y, a3);
        qs += q;
    }
    a0 += __shfl_xor(a0, 16); a0 += __shfl_xor(a0, 32);
    a1 += __shfl_xor(a1, 16); a1 += __shfl_xor(a1, 32);
    a2 += __shfl_xor(a2, 16); a2 += __shfl_xor(a2, 32);
    a3 += __shfl_xor(a3, 16); a3 += __shfl_xor(a3, 32);
    qs += __shfl_xor(qs, 16); qs += __shfl_xor(qs, 32);
    if (qt == 0) {
        unsigned rn = f8u[n * 16 + c];
        f32x2 lo = __builtin_amdgcn_cvt_pk_f32_fp8(rn, false);
        f32x2 hi = __builtin_amdgcn_cvt_pk_f32_fp8(rn, true);
        float4 xv = *(const float4*)&xi[c * 4];
        float4 o;
        o.x = xv.x * (a0 - qs * lo.x);
        o.y = xv.y * (a1 - qs * lo.y);
        o.z = xv.z * (a2 - qs * hi.x);
        o.w = xv.w * (a3 - qs * hi.y);
        *(float4*)&trans[n * 64 + c * 4] = o;
    }
}

// ---------------------------------------------------------------------------
// MFMA node kernel (R5-proven): 256 thr / 4 waves / 128 nodes, barrier-free
// layer loop, wave-private act rows, pre-transposed bf16 weights from global.
// ---------------------------------------------------------------------------
__global__ __launch_bounds__(256) void node_kernel(
    const unsigned short* __restrict__ fb16, const float* __restrict__ f,
    const float* __restrict__ macro_u, const float* __restrict__ source,
    const float* __restrict__ xi, const unsigned short* __restrict__ wp,
    const float* __restrict__ b_in, const float* __restrict__ b_hid,
    const float* __restrict__ b_out,
    const float* __restrict__ trans, float* __restrict__ out) {
    __shared__ __attribute__((aligned(16))) unsigned short act[128 * ACT_S];
    __shared__ float s0s[128], s1s[128], us[128], xif[64];

    const int t = threadIdx.x;
    const int wid = t >> 6;
    const int lane = t & 63;
    const int m = lane & 15;
    const int quad = lane >> 4;
    const int nodeBase = blockIdx.x * 128;
    const int gbase = nodeBase * 64;

    if (t < 128) {
        int n = nodeBase + t;
        us[t] = (n < NN) ? macro_u[n] : 0.f;
    }
    if (t < 64) xif[t] = xi[t];

#pragma unroll
    for (int i = 0; i < 8; i++) {
        int r = wid * 32 + i * 4 + (lane >> 4);
        int c = (lane & 15) * 4;
        uint2 v = {0u, 0u};
        if (nodeBase + r < NN) v = *(const uint2*)&fb16[gbase + r * 64 + c];
        *(uint2*)&act[r * ACT_S + c] = v;
    }

    const int rowbase = wid * 32;

    for (int l = 0; l < 5; l++) {
        const unsigned short* W = wp + l * 4096;
        const float* B = (l == 0) ? b_in : (l < 4 ? b_hid + (l - 1) * 64 : b_out);

        short8 Af[2][2], Bf[4][2];
#pragma unroll
        for (int rt = 0; rt < 2; rt++)
#pragma unroll
            for (int kk = 0; kk < 2; kk++)
                Af[rt][kk] = *(const short8*)&act[(rowbase + rt * 16 + m) * ACT_S + kk * 32 + quad * 8];
#pragma unroll
        for (int ct = 0; ct < 4; ct++)
#pragma unroll
            for (int kk = 0; kk < 2; kk++)
                Bf[ct][kk] = *(const short8*)&W[(ct * 16 + m) * 64 + kk * 32 + quad * 8];

        f32x4 acc[2][4];
#pragma unroll
        for (int rt = 0; rt < 2; rt++)
#pragma unroll
            for (int ct = 0; ct < 4; ct++) {
                acc[rt][ct] = (f32x4){0.f, 0.f, 0.f, 0.f};
                acc[rt][ct] = __builtin_amdgcn_mfma_f32_16x16x32_bf16(Af[rt][0], Bf[ct][0], acc[rt][ct], 0, 0, 0);
                acc[rt][ct] = __builtin_amdgcn_mfma_f32_16x16x32_bf16(Af[rt][1], Bf[ct][1], acc[rt][ct], 0, 0, 0);
            }

#pragma unroll
        for (int rt = 0; rt < 2; rt++)
#pragma unroll
            for (int ct = 0; ct < 4; ct++) {
                float bv = B[ct * 16 + m];
#pragma unroll
                for (int r = 0; r < 4; r++) {
                    int row = rowbase + rt * 16 + quad * 4 + r;
                    float val = acc[rt][ct][r] + bv;
                    val = (l < 4) ? fmaxf(val, 0.f) : tanhf(val);
                    act[row * ACT_S + ct * 16 + m] = f2bf(val);
                }
            }
    }
    __syncthreads();

    if (t < 128) {
        float u = us[t];
        float v0 = 0.f, v1 = 0.f, sxs2 = 0.f, sxi = 0.f;
        const short8* rp = (const short8*)&act[t * ACT_S];
#pragma unroll
        for (int c = 0; c < 8; c++) {
            short8 v = rp[c];
#pragma unroll
            for (int jj = 0; jj < 8; jj++) {
                float om = bf2f((unsigned short)v[jj]);
                float xv = xif[c * 8 + jj];
                float xs = xv + u;
                v0 += om;
                v1 += xs * om;
                sxs2 += xs * xs;
                sxi += xv;
            }
        }
        v0 *= WQc;
        v1 *= WQc;
        float c00 = WQc + REGc;
        float c01 = WQc * WQc * (sxi + 64.f * u);
        float c11 = WQc * WQc * sxs2 + REGc;
        float det = c00 * c11 - c01 * c01;
        float inv = 1.0f / det;
        s0s[t] = (c11 * v0 - c01 * v1) * inv;
        s1s[t] = (c00 * v1 - c01 * v0) * inv;
    }
    __syncthreads();

#pragma unroll
    for (int i = 0; i < 8; i++) {
        int e = (i * 256 + t) * 4;
        int nl = e >> 6;
        if (nodeBase + nl < NN) {
            int g = gbase + e;
            int c0 = e & 63;
            float4 fv = *(const float4*)&f[g];
            float4 sv = *(const float4*)&source[g];
            float4 tv = *(const float4*)&trans[g];
            float uu = us[nl];
            float sv0 = s0s[nl], sv1 = s1s[nl];
            float4 ov;
            float* ovp = (float*)&ov;
            const float* fp = (const float*)&fv;
            const float* sp = (const float*)&sv;
            const float* tp = (const float*)&tv;
#pragma unroll
            for (int jj = 0; jj < 4; jj++) {
                float om = bf2f(act[nl * ACT_S + c0 + jj]);
                float xs = xif[c0 + jj] + uu;
                float omst = om - WQc * (sv0 + xs * sv1);
                float val = fmaxf(fp[jj], 0.f) + DTc * (sp[jj] + omst - tp[jj]);
                ovp[jj] = fmaxf(val, 0.f);
            }
            *(float4*)&out[g] = ov;
        }
    }
}

extern "C" void kernel_launch(void* const* d_in, const int* in_sizes, int n_in,
                              void* d_out, int out_size, void* d_ws, size_t ws_size,
                              hipStream_t stream) {
    const float* f       = (const float*)d_in[0];
    const float* macro_u = (const float*)d_in[1];
    const float* source  = (const float*)d_in[2];
    const int*   esrc    = (const int*)d_in[3];
    const int*   edst    = (const int*)d_in[4];
    const float* ew      = (const float*)d_in[5];
    const float* xi      = (const float*)d_in[6];
    const float* w_in    = (const float*)d_in[7];
    const float* b_in    = (const float*)d_in[8];
    const float* w_hid   = (const float*)d_in[9];
    const float* b_hid   = (const float*)d_in[10];
    const float* w_out   = (const float*)d_in[11];
    const float* b_out   = (const float*)d_in[12];
    float* out = (float*)d_out;

    // workspace layout (8-byte entries first)
    u64* adj64 = (u64*)d_ws;                                   // TENT u64 = 25.6 MB
    unsigned int* adj4 = (unsigned int*)(adj64 + TENT);        // TENT u32 = 12.8 MB
    int* deg   = (int*)(adj4 + TENT);                          // NN
    int* bc    = deg + NN;                                     // MPAD
    int* offs  = bc + MPAD;                                    // MPAD
    int* bsums = offs + MPAD;                                  // 512
    int* node_offs = bsums + 512;                              // NN+1 (+pad)
    float* trans = (float*)(node_offs + NN + 8);               // NN*64
    unsigned int* f8u = (unsigned int*)(trans + (size_t)NN * 64);  // NN*16 uint
    unsigned short* fb16 = (unsigned short*)(f8u + (size_t)NN * 16); // NN*64
    unsigned short* wp = fb16 + (size_t)NN * 64;               // 5*4096

    // zero deg + bc (incl. scan pad)
    hipMemsetAsync(deg, 0, (size_t)(NN + MPAD) * sizeof(int), stream);

    prep_kernel<<<PRE_NB + WP_NB, 256, 0, stream>>>(f, (unsigned int*)fb16, f8u,
                                                    w_in, w_hid, w_out, wp);
    bin_count<<<NCH, 256, 0, stream>>>(esrc, edst, bc, deg);
    scan_blocks<<<SC_NB, 512, 0, stream>>>(bc, offs, bsums);
    scan_sums<<<1, 512, 0, stream>>>(bsums);
    bin_scatter<<<NCH, 256, 0, stream>>>(esrc, edst, ew, deg, offs, bsums, adj64);
    bucket_sort<<<NB, 256, 0, stream>>>(offs, bsums, adj64, adj4, node_offs);
    gather_kernel<<<(NN + 3) / 4, 256, 0, stream>>>(f8u, node_offs, adj4, xi, trans);
    node_kernel<<<(NN + 127) / 128, 256, 0, stream>>>(
        fb16, f, macro_u, source, xi, wp, b_in, b_hid, b_out, trans, out);
}